// Round 10
// baseline (648.403 us; speedup 1.0000x reference)
//
#include <hip/hip_runtime.h>

#define KK 64
#define TT 1024
#define BB 256
#define START_TAG 0
#define NB 16              // batches per forward block (one wave)
#define NWG (BB / NB)      // 16 forward blocks; blocks NWG..NWG+BB-1 do gold

typedef float f32x4 __attribute__((ext_vector_type(4)));
typedef int   i32x4 __attribute__((ext_vector_type(4)));
typedef short bf16x8 __attribute__((ext_vector_type(8)));  // 8 bf16 (4 VGPRs)

// v_cvt_pk_bf16_f32: no builtin on gfx950 (T12/m240) -> inline asm.
// dst low16 = bf16(a), high16 = bf16(b).
__device__ __forceinline__ unsigned cvt_pk_bf16(float a, float b) {
    unsigned r;
    asm("v_cvt_pk_bf16_f32 %0, %1, %2" : "=v"(r) : "v"(a), "v"(b));
    return r;
}
__device__ __forceinline__ float hi_lo(unsigned pk) {  // f32 of low-half bf16
    return __uint_as_float(pk << 16);
}
__device__ __forceinline__ float hi_hi(unsigned pk) {  // f32 of high-half bf16
    return __uint_as_float(pk & 0xffff0000u);
}
__device__ __forceinline__ f32x4 sel4(bool k, f32x4 a, f32x4 b) {
    f32x4 r; r.x = k ? a.x : b.x; r.y = k ? a.y : b.y;
    r.z = k ? a.z : b.z; r.w = k ? a.w : b.w; return r;
}

#define MM(A, B, C) C = __builtin_amdgcn_mfma_f32_16x16x32_bf16((A), (B), (C), 0, 0, 0);

// M-fragment (A-operand) setup for tile MT (output states 16MT..16MT+15),
// k-slab KS (source states 32KS..32KS+31). Slot enumeration mirrors the
// B-pack below: slots j=0..3 -> states 32KS+4g+j, j=4..7 -> 32KS+16+4g+(j-4).
// Any consistent A/B slot<->k enumeration cancels (HW A/B layouts symmetric).
#define SETM(MH, ML, MT, KS) { \
    const float* tp_ = trans + (16*(MT) + n) * KK + 32*(KS) + 4*g; \
    float m0_=__expf(tp_[0]),  m1_=__expf(tp_[1]),  m2_=__expf(tp_[2]),  m3_=__expf(tp_[3]); \
    float m4_=__expf(tp_[16]), m5_=__expf(tp_[17]), m6_=__expf(tp_[18]), m7_=__expf(tp_[19]); \
    unsigned h0_=cvt_pk_bf16(m0_,m1_), h1_=cvt_pk_bf16(m2_,m3_); \
    unsigned h2_=cvt_pk_bf16(m4_,m5_), h3_=cvt_pk_bf16(m6_,m7_); \
    i32x4 uh_ = {(int)h0_,(int)h1_,(int)h2_,(int)h3_}; \
    MH = __builtin_bit_cast(bf16x8, uh_); \
    unsigned l0_=cvt_pk_bf16(m0_-hi_lo(h0_), m1_-hi_hi(h0_)); \
    unsigned l1_=cvt_pk_bf16(m2_-hi_lo(h1_), m3_-hi_hi(h1_)); \
    unsigned l2_=cvt_pk_bf16(m4_-hi_lo(h2_), m5_-hi_hi(h2_)); \
    unsigned l3_=cvt_pk_bf16(m6_-hi_lo(h3_), m7_-hi_hi(h3_)); \
    i32x4 ul_ = {(int)l0_,(int)l1_,(int)l2_,(int)l3_}; \
    ML = __builtin_bit_cast(bf16x8, ul_); \
}

// feats for step T: lane (g,n) needs feats[(b0+n)][T][16mt+4g .. +3] for mt=0..3
// == exactly the C/D register layout (col=lane&15 batch, row=(lane>>4)*4+reg).
#define LOADF(D0, D1, D2, D3, T) { \
    int tc_ = (T) < TT ? (T) : (TT - 1); \
    const f32x4* p_ = (const f32x4*)(fbn + (size_t)tc_ * KK); \
    D0 = p_[0]; D1 = p_[4]; D2 = p_[8]; D3 = p_[12]; }

#define EXP4(D, S) { D.x=__expf(S.x); D.y=__expf(S.y); D.z=__expf(S.z); D.w=__expf(S.w); }

// One step: 24 MFMA (4 output tiles x 2 k-slabs x 3 precision passes) ->
// ef-scale -> (mask select) -> (renorm /4 steps, per-batch scale via
// ds_bpermute from lanes 0-15) -> repack C regs as next B-operand hi/lo.
#define DO_STEP(E0, E1, E2, E3, MVAL, HASM, RN) { \
    f32x4 a0 = {0,0,0,0}, a1 = {0,0,0,0}, a2 = {0,0,0,0}, a3 = {0,0,0,0}; \
    MM(Mh00, bh0, a0) MM(Mh10, bh0, a1) MM(Mh20, bh0, a2) MM(Mh30, bh0, a3) \
    MM(Mh01, bh1, a0) MM(Mh11, bh1, a1) MM(Mh21, bh1, a2) MM(Mh31, bh1, a3) \
    MM(Mh00, bl0, a0) MM(Mh10, bl0, a1) MM(Mh20, bl0, a2) MM(Mh30, bl0, a3) \
    MM(Mh01, bl1, a0) MM(Mh11, bl1, a1) MM(Mh21, bl1, a2) MM(Mh31, bl1, a3) \
    MM(Ml00, bh0, a0) MM(Ml10, bh0, a1) MM(Ml20, bh0, a2) MM(Ml30, bh0, a3) \
    MM(Ml01, bh1, a0) MM(Ml11, bh1, a1) MM(Ml21, bh1, a2) MM(Ml31, bh1, a3) \
    f32x4 v0 = a0 * (E0), v1 = a1 * (E1), v2 = a2 * (E2), v3 = a3 * (E3); \
    if (HASM) { bool km_ = ((MVAL) != 0.0f); \
        v0 = sel4(km_, v0, vc0); v1 = sel4(km_, v1, vc1); \
        v2 = sel4(km_, v2, vc2); v3 = sel4(km_, v3, vc3); } \
    if (RN) { \
        float sc_ = __int_as_float(__builtin_amdgcn_ds_bpermute(n4, __float_as_int(v0.y))); \
        sc_ = fmaxf(sc_, 1e-37f); \
        float inv_ = __builtin_amdgcn_rcpf(sc_); \
        v0 *= inv_; v1 *= inv_; v2 *= inv_; v3 *= inv_; \
        offset += __logf(sc_); \
    } \
    vc0 = v0; vc1 = v1; vc2 = v2; vc3 = v3; \
    unsigned p0 = cvt_pk_bf16(v0.x, v0.y), p1 = cvt_pk_bf16(v0.z, v0.w); \
    unsigned p2 = cvt_pk_bf16(v1.x, v1.y), p3 = cvt_pk_bf16(v1.z, v1.w); \
    unsigned p4 = cvt_pk_bf16(v2.x, v2.y), p5 = cvt_pk_bf16(v2.z, v2.w); \
    unsigned p6 = cvt_pk_bf16(v3.x, v3.y), p7 = cvt_pk_bf16(v3.z, v3.w); \
    i32x4 uh0_ = {(int)p0, (int)p1, (int)p2, (int)p3}; \
    i32x4 uh1_ = {(int)p4, (int)p5, (int)p6, (int)p7}; \
    bh0 = __builtin_bit_cast(bf16x8, uh0_); \
    bh1 = __builtin_bit_cast(bf16x8, uh1_); \
    unsigned q0 = cvt_pk_bf16(v0.x - hi_lo(p0), v0.y - hi_hi(p0)); \
    unsigned q1 = cvt_pk_bf16(v0.z - hi_lo(p1), v0.w - hi_hi(p1)); \
    unsigned q2 = cvt_pk_bf16(v1.x - hi_lo(p2), v1.y - hi_hi(p2)); \
    unsigned q3 = cvt_pk_bf16(v1.z - hi_lo(p3), v1.w - hi_hi(p3)); \
    unsigned q4 = cvt_pk_bf16(v2.x - hi_lo(p4), v2.y - hi_hi(p4)); \
    unsigned q5 = cvt_pk_bf16(v2.z - hi_lo(p5), v2.w - hi_hi(p5)); \
    unsigned q6 = cvt_pk_bf16(v3.x - hi_lo(p6), v3.y - hi_hi(p6)); \
    unsigned q7 = cvt_pk_bf16(v3.z - hi_lo(p7), v3.w - hi_hi(p7)); \
    i32x4 ul0_ = {(int)q0, (int)q1, (int)q2, (int)q3}; \
    i32x4 ul1_ = {(int)q4, (int)q5, (int)q6, (int)q7}; \
    bl0 = __builtin_bit_cast(bf16x8, ul0_); \
    bl1 = __builtin_bit_cast(bf16x8, ul1_); \
}

// Forward for 16 batches on one wave. Lane l = (g = l>>4, n = l&15):
// holds batch column n; output states 16mt + 4g + r across 4 acc tiles.
// HASM=0: all-ones-mask fast loop. HASM=1: per-step per-batch select.
template <int HASM>
__device__ __forceinline__ void forward16(
    const float* __restrict__ feats, const float* __restrict__ trans,
    const float* __restrict__ masks, float* __restrict__ out, int b0)
{
    const int l = threadIdx.x, g = l >> 4, n = l & 15;
    const int n4 = n << 2;

    bf16x8 Mh00, Mh01, Mh10, Mh11, Mh20, Mh21, Mh30, Mh31;
    bf16x8 Ml00, Ml01, Ml10, Ml11, Ml20, Ml21, Ml30, Ml31;
    SETM(Mh00, Ml00, 0, 0) SETM(Mh01, Ml01, 0, 1)
    SETM(Mh10, Ml10, 1, 0) SETM(Mh11, Ml11, 1, 1)
    SETM(Mh20, Ml20, 2, 0) SETM(Mh21, Ml21, 2, 1)
    SETM(Mh30, Ml30, 3, 0) SETM(Mh31, Ml31, 3, 1)

    // a0 one-hot at state START=0 -> B slot (g=0, j=0); bf16(1.0) = 0x3F80
    i32x4 z4 = {0, 0, 0, 0};
    i32x4 h4 = {(g == 0) ? 0x3F80 : 0, 0, 0, 0};
    bf16x8 bh0 = __builtin_bit_cast(bf16x8, h4);
    bf16x8 bh1 = __builtin_bit_cast(bf16x8, z4);
    bf16x8 bl0 = __builtin_bit_cast(bf16x8, z4);
    bf16x8 bl1 = __builtin_bit_cast(bf16x8, z4);
    f32x4 vc0 = {(g == 0) ? 1.0f : 0.0f, 0, 0, 0};
    f32x4 vc1 = {0, 0, 0, 0}, vc2 = {0, 0, 0, 0}, vc3 = {0, 0, 0, 0};
    float offset = 0.0f;

    const float* fbn  = feats + ((size_t)(b0 + n) * TT) * KK + 4 * g;
    const float* mrow = masks + (size_t)(b0 + n) * TT;

    f32x4 fA0, fA1, fA2, fA3, fB0, fB1, fB2, fB3;
    f32x4 eA0, eA1, eA2, eA3, eB0, eB1, eB2, eB3;
    LOADF(fA0, fA1, fA2, fA3, 1)
    LOADF(fB0, fB1, fB2, fB3, 2)
    EXP4(eA0, fA0) EXP4(eA1, fA1) EXP4(eA2, fA2) EXP4(eA3, fA3)

    // invariant at group head: eA = ef(t0), fB = feats(t0+1)
    for (int t0 = 1; t0 + 3 < TT; t0 += 4) {
        LOADF(fA0, fA1, fA2, fA3, t0 + 2)
        EXP4(eB0, fB0) EXP4(eB1, fB1) EXP4(eB2, fB2) EXP4(eB3, fB3)
        DO_STEP(eA0, eA1, eA2, eA3, HASM ? mrow[t0] : 1.0f, HASM, 0)
        LOADF(fB0, fB1, fB2, fB3, t0 + 3)
        EXP4(eA0, fA0) EXP4(eA1, fA1) EXP4(eA2, fA2) EXP4(eA3, fA3)
        DO_STEP(eB0, eB1, eB2, eB3, HASM ? mrow[t0 + 1] : 1.0f, HASM, 0)
        LOADF(fA0, fA1, fA2, fA3, t0 + 4)
        EXP4(eB0, fB0) EXP4(eB1, fB1) EXP4(eB2, fB2) EXP4(eB3, fB3)
        DO_STEP(eA0, eA1, eA2, eA3, HASM ? mrow[t0 + 2] : 1.0f, HASM, 0)
        LOADF(fB0, fB1, fB2, fB3, t0 + 5)
        EXP4(eA0, fA0) EXP4(eA1, fA1) EXP4(eA2, fA2) EXP4(eA3, fA3)
        DO_STEP(eB0, eB1, eB2, eB3, HASM ? mrow[t0 + 3] : 1.0f, HASM, 1)
    }
    // tail: t = 1021 (eA), 1022 (eB), 1023 (eA); <=3 steps since renorm
    EXP4(eB0, fB0) EXP4(eB1, fB1) EXP4(eB2, fB2) EXP4(eB3, fB3)
    LOADF(fA0, fA1, fA2, fA3, TT - 1)
    DO_STEP(eA0, eA1, eA2, eA3, HASM ? mrow[TT - 3] : 1.0f, HASM, 0)
    EXP4(eA0, fA0) EXP4(eA1, fA1) EXP4(eA2, fA2) EXP4(eA3, fA3)
    DO_STEP(eB0, eB1, eB2, eB3, HASM ? mrow[TT - 2] : 1.0f, HASM, 0)
    DO_STEP(eA0, eA1, eA2, eA3, HASM ? mrow[TT - 1] : 1.0f, HASM, 0)

    // fwd_score[n] = offset[n] + log(sum over 64 states)
    float p = (vc0.x + vc0.y + vc0.z + vc0.w) + (vc1.x + vc1.y + vc1.z + vc1.w)
            + (vc2.x + vc2.y + vc2.z + vc2.w) + (vc3.x + vc3.y + vc3.z + vc3.w);
    p += __shfl_xor(p, 16, 64);
    p += __shfl_xor(p, 32, 64);
    float score = offset + __logf(p);    // lanes 0..15 hold batches 0..15
    float ssum = score;
    ssum += __shfl_xor(ssum, 8, 64);
    ssum += __shfl_xor(ssum, 4, 64);
    ssum += __shfl_xor(ssum, 2, 64);
    ssum += __shfl_xor(ssum, 1, 64);
    if (l == 0) atomicAdd(out, ssum * (1.0f / (float)BB));
}

// Blocks 0..NWG-1: MFMA forward for 16 batches each (all-ones detect -> fast).
// Blocks NWG..NWG+BB-1: gold score for one batch each (concurrent, ~12us).
__global__ __launch_bounds__(64)
__attribute__((amdgpu_waves_per_eu(1, 1)))
void crf_kernel(
    const float* __restrict__ feats,
    const float* __restrict__ trans,
    const float* __restrict__ masks,
    const int*   __restrict__ tags,
    float* __restrict__ out)
{
    const int bid = blockIdx.x;
    const int l = threadIdx.x;

    if (bid < NWG) {
        const int b0 = bid * NB;
        int ok = 1;
        for (int nn = 0; nn < NB; ++nn) {
            const f32x4* mr = (const f32x4*)(masks + (size_t)(b0 + nn) * TT);
            for (int q = l; q < TT / 4; q += 64) {
                f32x4 mv = mr[q];
                ok &= (mv.x == 1.0f) && (mv.y == 1.0f) &&
                      (mv.z == 1.0f) && (mv.w == 1.0f);
            }
        }
        if (__ballot(ok != 0) == ~0ull)
            forward16<0>(feats, trans, masks, out, b0);
        else
            forward16<1>(feats, trans, masks, out, b0);
    } else {
        const int b = bid - NWG;
        const float* fb = feats + (size_t)b * TT * KK;
        const float* mb = masks + (size_t)b * TT;
        const int* tg = tags + b * TT;
        float gsum = 0.f;
        for (int t = 1 + l; t < TT; t += 64) {
            int ct = tg[t], pt = tg[t - 1];
            gsum += (trans[ct * KK + pt] + fb[t * KK + ct]) * mb[t];
        }
        #pragma unroll
        for (int off = 32; off >= 1; off >>= 1)
            gsum += __shfl_xor(gsum, off, 64);
        if (l == 0) atomicAdd(out, -gsum * (1.0f / (float)BB));
    }
}

extern "C" void kernel_launch(void* const* d_in, const int* in_sizes, int n_in,
                              void* d_out, int out_size, void* d_ws, size_t ws_size,
                              hipStream_t stream) {
    const float* feats = (const float*)d_in[0];
    const float* trans = (const float*)d_in[1];
    const int*   tags  = (const int*)d_in[2];
    const float* masks = (const float*)d_in[3];
    float* out = (float*)d_out;

    hipMemsetAsync(out, 0, sizeof(float), stream);  // atomicAdd accumulator
    crf_kernel<<<NWG + BB, 64, 0, stream>>>(feats, trans, masks, tags, out);
}

// Round 11
// 268.124 us; speedup vs baseline: 2.4183x; 2.4183x over previous
//
#include <hip/hip_runtime.h>

#define KK 64
#define TT 1024
#define BB 256
#define START_TAG 0

typedef float v2f __attribute__((ext_vector_type(2)));
typedef float v4f __attribute__((ext_vector_type(4)));

__device__ __forceinline__ float lane_bcast(float v, int lane) {
    return __int_as_float(__builtin_amdgcn_readlane(__float_as_int(v), lane));
}

// Packed dual-fp32 VALU ops (VOP3P). Non-volatile register-only asm: the
// scheduler may interleave these freely with the ds_read lgkmcnt waits.
#define PKMUL(D, S, E) asm("v_pk_mul_f32 %0, %1, %2"     : "=v"(D) : "v"(S), "v"(E));
#define PKFMA(D, S, E) asm("v_pk_fma_f32 %0, %1, %2, %0" : "+v"(D) : "v"(S), "v"(E));
#define PKADD(D, X, Y) asm("v_pk_add_f32 %0, %1, %2"     : "=v"(D) : "v"(X), "v"(Y));

// et pair k: (exp(trans[i][2k]), exp(trans[i][2k+1])) — one v2f per 2 states,
// 32 pairs = 64 VGPRs, pinned so the compiler cannot rematerialize.
#define DECLP(k) v2f et##k = { __expf(trow[2*(k)]), __expf(trow[2*(k)+1]) };
#define PINP(p,q,r,s) asm volatile("" : "+v"(et##p), "+v"(et##q), "+v"(et##r), "+v"(et##s));

// One recurrence step (r4 structure — the measured 530-cyc floor champion):
//   1 ds_write_b32 (scatter a[i]; 2-way bank alias = free)
//  16 ds_read_b128 (all lanes read the SAME address = conflict-free broadcast,
//     4 floats = 2 pairs per instruction)
//  16 v_pk_fma/pk_mul (64 MACs) + 3 pk_add + 1 add + scale (+ select if HASM)
// No barrier, no double buffer: LDS ops of a single wave execute IN ORDER,
// so the wave's own write is visible to its subsequent reads; lgkmcnt only
// gates VALU consumption of read data (compiler inserts fine-grained waits).
// HASM is a literal 0/1: the fast path compiles WITHOUT the cmp+cndmask in
// the fully-exposed dependent tail.
#define DO_STEP(EFV, HASM, MKV, RN) { \
    abuf[i] = a; \
    const v4f* rb_ = reinterpret_cast<const v4f*>(abuf); \
    v4f w0 = rb_[0],  w1 = rb_[1],  w2 = rb_[2],  w3 = rb_[3]; \
    v4f w4 = rb_[4],  w5 = rb_[5],  w6 = rb_[6],  w7 = rb_[7]; \
    v4f w8 = rb_[8],  w9 = rb_[9],  w10 = rb_[10], w11 = rb_[11]; \
    v4f w12 = rb_[12], w13 = rb_[13], w14 = rb_[14], w15 = rb_[15]; \
    v2f acc0, acc1, acc2, acc3; \
    PKMUL(acc0, w0.xy, et0)   PKMUL(acc1, w0.zw, et1) \
    PKMUL(acc2, w1.xy, et2)   PKMUL(acc3, w1.zw, et3) \
    PKFMA(acc0, w2.xy, et4)   PKFMA(acc1, w2.zw, et5) \
    PKFMA(acc2, w3.xy, et6)   PKFMA(acc3, w3.zw, et7) \
    PKFMA(acc0, w4.xy, et8)   PKFMA(acc1, w4.zw, et9) \
    PKFMA(acc2, w5.xy, et10)  PKFMA(acc3, w5.zw, et11) \
    PKFMA(acc0, w6.xy, et12)  PKFMA(acc1, w6.zw, et13) \
    PKFMA(acc2, w7.xy, et14)  PKFMA(acc3, w7.zw, et15) \
    PKFMA(acc0, w8.xy, et16)  PKFMA(acc1, w8.zw, et17) \
    PKFMA(acc2, w9.xy, et18)  PKFMA(acc3, w9.zw, et19) \
    PKFMA(acc0, w10.xy, et20) PKFMA(acc1, w10.zw, et21) \
    PKFMA(acc2, w11.xy, et22) PKFMA(acc3, w11.zw, et23) \
    PKFMA(acc0, w12.xy, et24) PKFMA(acc1, w12.zw, et25) \
    PKFMA(acc2, w13.xy, et26) PKFMA(acc3, w13.zw, et27) \
    PKFMA(acc0, w14.xy, et28) PKFMA(acc1, w14.zw, et29) \
    PKFMA(acc2, w15.xy, et30) PKFMA(acc3, w15.zw, et31) \
    v2f accA, accB, accC; \
    PKADD(accA, acc0, acc1) \
    PKADD(accB, acc2, acc3) \
    PKADD(accC, accA, accB) \
    float s_ = accC.x + accC.y; \
    float anew = s_ * (EFV); \
    if (HASM) { a = ((MKV) != 0.0f) ? anew : a; } else { a = anew; } \
    if (RN) { \
        float a1 = fmaxf(lane_bcast(a, 1), 1e-37f); \
        a *= __builtin_amdgcn_rcpf(a1); \
        offset += __logf(a1); \
    } \
}

// Forward algorithm in the probability domain. One wave per batch element;
// lane i owns state i, et pairs hold exp(trans[i][2k..2k+1]).
//
// Session evidence (rounds 0-10): the recurrence floors at ~530 cyc/step =
// ~150 cyc LDS write->read round trip + ~200 cyc in-order b128 return stream
// + ~180 cyc dependent tail at the ~4.5 cyc/inst single-wave issue cadence.
// Six broadcast mechanisms (readlane 690, LDS-b128 530, 4-wave split 650,
// swizzle+DPP 620, permlane+DPP 600-645, two-pipe hybrid 525) and two
// alternative decompositions (multi-wave +23%, MFMA 16-batch +175%) all
// measured >= this floor. Not a HW roofline (HBM 2.8%, VALU 14%) — a
// serial-recurrence latency wall of the 1-wave-per-batch decomposition.
//
// This version = floor champion (r4) + all-ones-mask fast path (drops the
// cmp+cndmask from the exposed dependent tail; generic masked loop is the
// verbatim-r4 fallback). Renorm once per 4 steps by a[1] (wave-uniform
// positive scale is exact via offset += log(scale)).
__global__ __launch_bounds__(64)
__attribute__((amdgpu_waves_per_eu(1, 1)))
void crf_forward_kernel(
    const float* __restrict__ feats,
    const float* __restrict__ trans,
    const float* __restrict__ masks,
    const int*   __restrict__ tags,
    float* __restrict__ out)
{
    const int b = blockIdx.x;
    const int i = threadIdx.x;

    __shared__ __align__(16) float abuf[KK];

    const float* trow = trans + i * KK;
    DECLP(0)  DECLP(1)  DECLP(2)  DECLP(3)  DECLP(4)  DECLP(5)  DECLP(6)  DECLP(7)
    DECLP(8)  DECLP(9)  DECLP(10) DECLP(11) DECLP(12) DECLP(13) DECLP(14) DECLP(15)
    DECLP(16) DECLP(17) DECLP(18) DECLP(19) DECLP(20) DECLP(21) DECLP(22) DECLP(23)
    DECLP(24) DECLP(25) DECLP(26) DECLP(27) DECLP(28) DECLP(29) DECLP(30) DECLP(31)
    PINP(0,1,2,3)     PINP(4,5,6,7)     PINP(8,9,10,11)   PINP(12,13,14,15)
    PINP(16,17,18,19) PINP(20,21,22,23) PINP(24,25,26,27) PINP(28,29,30,31)

    float a = (i == START_TAG) ? 1.0f : 0.0f;  // exp(alpha0)
    float offset = 0.0f;                        // running log-scale

    const float* fb = feats + (size_t)b * TT * KK;
    const float* mb = masks + (size_t)b * TT;

    // all-ones mask detection (exact equality, ballot across the wave)
    int okm = 1;
    for (int t = 1 + i; t < TT; t += 64) okm &= (mb[t] == 1.0f) ? 1 : 0;
    bool allones = (__ballot(okm != 0) == ~0ull);

    if (allones) {
        // ---- fast path: no mask handling anywhere in the hot loop ----
        float cf0 = fb[1 * KK + i], cf1 = fb[2 * KK + i];
        float cf2 = fb[3 * KK + i], cf3 = fb[4 * KK + i];
        // groups t0 = 1,5,...,1017 (steps 1..1020), then 3 tail steps
        for (int t0 = 1; t0 + 3 < TT; t0 += 4) {
            int p0 = (t0 + 4 < TT) ? t0 + 4 : TT - 1;
            int p1 = (t0 + 5 < TT) ? t0 + 5 : TT - 1;
            int p2 = (t0 + 6 < TT) ? t0 + 6 : TT - 1;
            int p3 = (t0 + 7 < TT) ? t0 + 7 : TT - 1;
            float nf0 = fb[p0 * KK + i], nf1 = fb[p1 * KK + i];
            float nf2 = fb[p2 * KK + i], nf3 = fb[p3 * KK + i];
            // exp(feat): inputs prefetched a full group ago -> off crit path
            float ef0 = __expf(cf0), ef1 = __expf(cf1);
            float ef2 = __expf(cf2), ef3 = __expf(cf3);
            DO_STEP(ef0, 0, 0.0f, 0)
            DO_STEP(ef1, 0, 0.0f, 0)
            DO_STEP(ef2, 0, 0.0f, 0)
            DO_STEP(ef3, 0, 0.0f, 1)   // renorm folded into 4th step
            cf0 = nf0; cf1 = nf1; cf2 = nf2; cf3 = nf3;
        }
        // tail steps t = 1021..1023 (prefetched into cf0..cf2);
        // <= 3 steps since last renorm -> no overflow risk
        float ef0 = __expf(cf0), ef1 = __expf(cf1), ef2 = __expf(cf2);
        DO_STEP(ef0, 0, 0.0f, 0)
        DO_STEP(ef1, 0, 0.0f, 0)
        DO_STEP(ef2, 0, 0.0f, 0)
    } else {
        // ---- generic path: verbatim r4 structure (per-step mask select) ----
        float cf0 = fb[1 * KK + i], cf1 = fb[2 * KK + i];
        float cf2 = fb[3 * KK + i], cf3 = fb[4 * KK + i];
        float cm0 = mb[1], cm1 = mb[2], cm2 = mb[3], cm3 = mb[4];
        for (int t0 = 1; t0 < TT; t0 += 4) {
            int p0 = (t0 + 4 < TT) ? t0 + 4 : TT - 1;
            int p1 = (t0 + 5 < TT) ? t0 + 5 : TT - 1;
            int p2 = (t0 + 6 < TT) ? t0 + 6 : TT - 1;
            int p3 = (t0 + 7 < TT) ? t0 + 7 : TT - 1;
            float nf0 = fb[p0 * KK + i], nf1 = fb[p1 * KK + i];
            float nf2 = fb[p2 * KK + i], nf3 = fb[p3 * KK + i];
            float nm0 = mb[p0], nm1 = mb[p1], nm2 = mb[p2], nm3 = mb[p3];
            float ef0 = __expf(cf0), ef1 = __expf(cf1);
            float ef2 = __expf(cf2), ef3 = __expf(cf3);
            DO_STEP(ef0, 1, cm0, 0)
            DO_STEP(ef1, 1, cm1, 0)
            DO_STEP(ef2, 1, cm2, 0)
            float m3 = (t0 + 3 < TT) ? cm3 : 0.0f;   // last group clips t=1024
            DO_STEP(ef3, 1, m3, 1)                   // renorm folded into 4th
            cf0 = nf0; cf1 = nf1; cf2 = nf2; cf3 = nf3;
            cm0 = nm0; cm1 = nm1; cm2 = nm2; cm3 = nm3;
        }
    }

    // forward_score = offset + log(sum_j a_j)
    float s = a;
    #pragma unroll
    for (int off = 32; off >= 1; off >>= 1)
        s += __shfl_xor(s, off, 64);
    float fwd_score = offset + __logf(s);

    // ---- fused gold score: sum_t (trans[ct,pt] + feats[t,ct]) * mask[t] ----
    const int* tg = tags + b * TT;
    float g = 0.f;
    for (int t = 1 + i; t < TT; t += 64) {
        int ct = tg[t], pt = tg[t - 1];
        g += (trans[ct * KK + pt] + fb[t * KK + ct]) * mb[t];
    }
    #pragma unroll
    for (int off = 32; off >= 1; off >>= 1)
        g += __shfl_xor(g, off, 64);

    if (i == 0) atomicAdd(out, (fwd_score - g) * (1.0f / (float)BB));
}

extern "C" void kernel_launch(void* const* d_in, const int* in_sizes, int n_in,
                              void* d_out, int out_size, void* d_ws, size_t ws_size,
                              hipStream_t stream) {
    const float* feats = (const float*)d_in[0];
    const float* trans = (const float*)d_in[1];
    const int*   tags  = (const int*)d_in[2];
    const float* masks = (const float*)d_in[3];
    float* out = (float*)d_out;

    hipMemsetAsync(out, 0, sizeof(float), stream);  // atomicAdd accumulator
    crf_forward_kernel<<<BB, 64, 0, stream>>>(feats, trans, masks, tags, out);
}